// Round 1
// baseline (285.771 us; speedup 1.0000x reference)
//
#include <hip/hip_runtime.h>
#include <hip/hip_bf16.h>

// ---------------------------------------------------------------------------
// BF_NIR_conv, round 3:
//   k0 prep    : convert W1/W2/W3 -> bf16 N-major  +  transpose featc ->
//                Ft[16384][256] bf16 (LDS-tiled, coalesced both sides)
//   k1 u_gemm  : U[pos][256] = Ft[pos][:] @ W1[0:256][:]  -- LDS-free MFMA,
//                1024 blocks (4/CU), fragments straight from global
//   k2 main    : 512-thread blocks (8 waves, same 64-row tile -> 24 waves/CU),
//                chunk-swizzled LDS (conflict-free b128), cvt_pk bf16 pack
// ---------------------------------------------------------------------------

using bf16x8 = __attribute__((ext_vector_type(8))) __bf16;
using f32x4  = __attribute__((ext_vector_type(4))) float;

__device__ __forceinline__ float bf2f(unsigned short u){
  unsigned int x = ((unsigned int)u) << 16;
  return __builtin_bit_cast(float, x);
}
__device__ __forceinline__ unsigned short f2bf(float f){
  unsigned int x = __builtin_bit_cast(unsigned int, f);
  unsigned int r = x + 0x7fffu + ((x >> 16) & 1u);
  return (unsigned short)(r >> 16);
}
// packed f32x2 -> bf16x2 (RNE), 1 VALU op for 2 elements (no builtin on gfx950)
__device__ __forceinline__ unsigned int cvt_pk_bf16(float lo, float hi){
  unsigned int r;
  asm("v_cvt_pk_bf16_f32 %0, %1, %2" : "=v"(r) : "v"(lo), "v"(hi));
  return r;
}
__device__ __forceinline__ bf16x8 ld8(const ushort* p){
  uint4 r = *(const uint4*)p;
  return __builtin_bit_cast(bf16x8, r);
}

// 16B-chunk swizzles: slot' = (slot + period + 2*row) mod 8.  Makes every
// b128 access pattern in main (column-slice reads across rows, row writes)
// land 8 lanes per 16B bank-group = optimal.  Row stride 256 / 128 ushort.
__device__ __forceinline__ int swz256i(int row, int c){
  return row*256 + ((c & ~0x38) | ((((c>>3) + (c>>6) + 2*row) & 7) << 3));
}
__device__ __forceinline__ int swz128i(int row, int c){
  return row*128 + ((c & ~0x38) | ((((c>>3) + (c>>6) + 2*row) & 7) << 3));
}
// transpose-tile variant (row coeff 1: spreads the fixed-column b16 writes)
__device__ __forceinline__ int swzT(int row, int c){
  return row*256 + ((c & ~0x38) | ((((c>>3) + (c>>6) + row) & 7) << 3));
}

struct RowMeta { int spos; float relY, relX; };
__device__ __forceinline__ RowMeta row_meta(int Y, int X, int br){
  int ivx = br >> 1, ivy = br & 1;   // branch order: (vx,vy)=(-,-),(-,+),(+,-),(+,+)
  int validY, iy; float relY;
  if (ivx == 0){ validY = (Y >= 1);   iy = (Y-1) >> 1; relY = (Y & 1) ?  0.5f :  1.5f; }
  else         { validY = (Y <= 254); iy = (Y+1) >> 1; relY = (Y & 1) ? -1.5f : -0.5f; }
  int validX, ix; float relX;
  if (ivy == 0){ validX = (X >= 1);   ix = (X-1) >> 1; relX = (X & 1) ?  0.5f :  1.5f; }
  else         { validX = (X <= 254); ix = (X+1) >> 1; relX = (X & 1) ? -1.5f : -0.5f; }
  RowMeta r;
  if (validY && validX){ r.spos = iy*128 + ix; r.relY = relY; r.relX = relX; }
  else { r.spos = -1; r.relY = (float)Y + 0.5f - 128.0f; r.relX = (float)X + 0.5f - 128.0f; }
  return r;
}

// --- k0: weight convert + featc transpose ----------------------------------
__global__ __launch_bounds__(256) void prep(
    const float* __restrict__ W1, const float* __restrict__ W2,
    const float* __restrict__ W3,
    const float* __restrict__ lr_guide, const float* __restrict__ feat,
    ushort* __restrict__ W1t,   // [256][384]
    ushort* __restrict__ W2t,   // [128][256]
    ushort* __restrict__ W3t,   // [32][128]
    ushort* __restrict__ Ft)    // [16384][256]  featc transposed, bf16
{
  __shared__ ushort T[32*256];
  const int b = blockIdx.x, t = threadIdx.x;
  if (b < 512){
    const int pos0 = b*32;
    #pragma unroll
    for (int i=0;i<32;i++){
      int k = i*8 + (t>>5), pos = t & 31;
      const float* src = (k < 128) ? lr_guide : feat;
      T[swzT(pos, k)] = f2bf(src[(size_t)(k & 127)*16384 + pos0 + pos]);
    }
    __syncthreads();
    const int pos = t>>3, ul = t&7;
    #pragma unroll
    for (int jj=0;jj<4;jj++){
      int c = ul*32 + jj*8;
      union { uint4 v; ushort s[8]; } x;
      x.v = *(const uint4*)&T[swzT(pos, c)];
      *(uint4*)&Ft[(size_t)(pos0+pos)*256 + c] = x.v;
    }
  } else {
    int i = (b-512)*256 + t;                       // 384 blocks -> i < 98304
    { int k = i >> 8, n = i & 255; W1t[n*384 + k] = f2bf(W1[i]); }
    if (i < 32768){ int k = i >> 7, n = i & 127; W2t[n*256 + k] = f2bf(W2[i]); }
    if (i < 4096) { int k = i >> 5, n = i & 31;  W3t[n*128 + k] = f2bf(W3[i]); }
  }
}

// --- k1: U GEMM, LDS-free: U[pos][n] = sum_k Ft[pos][k] * W1[k][n] ----------
__global__ __launch_bounds__(256) void u_gemm(
    const ushort* __restrict__ Ft, const ushort* __restrict__ W1t,
    ushort* __restrict__ U)                        // [16384][256]
{
  const int t = threadIdx.x;
  const int w = t >> 6, lane = t & 63, quad = lane >> 4, l15 = lane & 15;
  const int pos0 = (blockIdx.x >> 1) * 32;         // 512 pos-blocks
  const int nh   = blockIdx.x & 1;                 // 2 n-halves of 128

  f32x4 acc[2][2];
  #pragma unroll
  for (int a=0;a<2;a++) { acc[a][0] = f32x4{0.f,0.f,0.f,0.f}; acc[a][1] = f32x4{0.f,0.f,0.f,0.f}; }

  #pragma unroll
  for (int kt=0; kt<8; kt++){
    const int ko = kt*32 + quad*8;
    bf16x8 a0 = ld8(&Ft[(size_t)(pos0 +      l15)*256 + ko]);
    bf16x8 a1 = ld8(&Ft[(size_t)(pos0 + 16 + l15)*256 + ko]);
    bf16x8 b0 = ld8(&W1t[(size_t)(nh*128 + w*32 +      l15)*384 + ko]);
    bf16x8 b1 = ld8(&W1t[(size_t)(nh*128 + w*32 + 16 + l15)*384 + ko]);
    acc[0][0] = __builtin_amdgcn_mfma_f32_16x16x32_bf16(a0, b0, acc[0][0], 0,0,0);
    acc[0][1] = __builtin_amdgcn_mfma_f32_16x16x32_bf16(a0, b1, acc[0][1], 0,0,0);
    acc[1][0] = __builtin_amdgcn_mfma_f32_16x16x32_bf16(a1, b0, acc[1][0], 0,0,0);
    acc[1][1] = __builtin_amdgcn_mfma_f32_16x16x32_bf16(a1, b1, acc[1][1], 0,0,0);
  }
  #pragma unroll
  for (int mt=0; mt<2; mt++)
    #pragma unroll
    for (int nt=0; nt<2; nt++){
      int n = nh*128 + w*32 + nt*16 + l15;
      #pragma unroll
      for (int r=0; r<4; r++)
        U[(size_t)(pos0 + mt*16 + quad*4 + r)*256 + n] = f2bf(acc[mt][nt][r]);
    }
}

// --- k2: fused main. 512 threads, 16 pixels x 4 branches = 64 rows ----------
__global__ __launch_bounds__(512, 6) void main_fused(
    const float* __restrict__ feat,      // [128][16384]
    const float* __restrict__ hr_guide,  // [128][65536]
    const float* __restrict__ W1,        // [386][256] fp32 (rel rows 384/385)
    const float* __restrict__ b1v,
    const float* __restrict__ b2v,
    const float* __restrict__ b3v,
    const ushort* __restrict__ U,        // [16384][256] bf16
    const ushort* __restrict__ W1t,      // [256][384] bf16 (N-major)
    const ushort* __restrict__ W2t,      // [128][256] bf16 (N-major)
    const ushort* __restrict__ W3t,      // [32][128]  bf16 (N-major)
    float* __restrict__ outp)            // [32][65536]
{
  // LDS 43.5 KB -> 3 blocks/CU x 8 waves = 24 waves/CU.
  __shared__ __align__(16) ushort A1[64*256];  // h1 (hr-stage rows0..15 / h2 aliased)
  __shared__ __align__(16) ushort Gt[16*256];
  __shared__ __align__(16) float  w1r[2][256];
  __shared__ float gcs[64];
  __shared__ float wgt[64];

  const int t = threadIdx.x;
  const int w = t >> 6, lane = t & 63, quad = lane >> 4, l15 = lane & 15;
  const int Y  = blockIdx.x >> 4;
  const int X0 = (blockIdx.x & 15) << 4;

  // ---- phase 0: U preload (32 cols/thread), hr staging, w1r, gc ----
  const int m   = t >> 3;            // h1 row handled by this thread
  const int ul  = t & 7;             // column octant: c0 = ul*32
  const int pix = m >> 2, br = m & 3;
  RowMeta rm = row_meta(Y, X0 + pix, br);

  uint4 uu[4];
  if (rm.spos >= 0){
    const ushort* Up = U + (size_t)rm.spos*256 + ul*32;
    #pragma unroll
    for (int j=0; j<4; j++) uu[j] = *(const uint4*)(Up + j*8);
  } else {
    #pragma unroll
    for (int j=0; j<4; j++) uu[j] = make_uint4(0u,0u,0u,0u);
  }

  {
    int ch = t >> 2, xq = t & 3;     // 512 threads cover 128 ch x 4 x-quads
    float4 v = *(const float4*)(hr_guide + (size_t)ch*65536 + Y*256 + X0 + xq*4);
    A1[swz256i(xq*4+0, ch)] = f2bf(v.x);
    A1[swz256i(xq*4+1, ch)] = f2bf(v.y);
    A1[swz256i(xq*4+2, ch)] = f2bf(v.z);
    A1[swz256i(xq*4+3, ch)] = f2bf(v.w);
  }
  w1r[t>>8][t&255] = W1[(size_t)(384 + (t>>8))*256 + (t&255)];

  if (t < 64){
    RowMeta g = row_meta(Y, X0 + (t>>2), t & 3);
    float gc = 0.0f;
    if (g.spos >= 0){
      int bpos = (Y>>1)*128 + ((X0 + (t>>2)) >> 1);
      #pragma unroll
      for (int cc=0; cc<3; cc++)
        gc += feat[(size_t)(124+cc)*16384 + bpos] * feat[(size_t)(124+cc)*16384 + g.spos];
    }
    gcs[t] = gc;
  }
  __syncthreads();                                   // sync1

  // ---- phase 1: softmax weights + G MFMA (M=16 pix, N=256, K=128) ----
  if (t < 16){
    float g0 = gcs[t*4+0], g1 = gcs[t*4+1], g2 = gcs[t*4+2], g3 = gcs[t*4+3];
    float mx = fmaxf(fmaxf(g0,g1), fmaxf(g2,g3));
    float e0 = __expf(g0-mx), e1 = __expf(g1-mx), e2 = __expf(g2-mx), e3 = __expf(g3-mx);
    float inv = 1.0f/(e0+e1+e2+e3);
    wgt[t*4+0]=e0*inv; wgt[t*4+1]=e1*inv; wgt[t*4+2]=e2*inv; wgt[t*4+3]=e3*inv;
  }
  {
    f32x4 accg[2] = { f32x4{0.f,0.f,0.f,0.f}, f32x4{0.f,0.f,0.f,0.f} };
    #pragma unroll
    for (int kt=0; kt<4; kt++){
      bf16x8 a = ld8(&A1[swz256i(l15, kt*32 + quad*8)]);          // hr-stage
      #pragma unroll
      for (int nt=0; nt<2; nt++){
        bf16x8 b = ld8(&W1t[(size_t)(w*32 + nt*16 + l15)*384 + 256 + kt*32 + quad*8]);
        accg[nt] = __builtin_amdgcn_mfma_f32_16x16x32_bf16(a, b, accg[nt], 0,0,0);
      }
    }
    #pragma unroll
    for (int nt=0; nt<2; nt++){
      int n = w*32 + nt*16 + l15;
      float bv = b1v[n];
      #pragma unroll
      for (int r=0; r<4; r++)
        Gt[swz256i(quad*4+r, n)] = f2bf(accg[nt][r] + bv);        // C/D: row=quad*4+r
    }
  }
  __syncthreads();                                   // sync2

  // ---- phase 2: h1 assembly into A1 (32 cols/thread, cvt_pk pack) ----
  {
    const float relY = rm.relY, relX = rm.relX;
    #pragma unroll
    for (int jj=0; jj<4; jj++){
      const int c = ul*32 + jj*8;
      union { uint4 v; ushort s[8]; } gu, uv;
      gu.v = *(const uint4*)&Gt[swz256i(pix, c)];
      uv.v = uu[jj];
      float r0[8], r1[8];
      *(float4*)&r0[0] = *(const float4*)&w1r[0][c];
      *(float4*)&r0[4] = *(const float4*)&w1r[0][c+4];
      *(float4*)&r1[0] = *(const float4*)&w1r[1][c];
      *(float4*)&r1[4] = *(const float4*)&w1r[1][c+4];
      unsigned int ov[4];
      #pragma unroll
      for (int i=0; i<4; i++){
        float h0 = bf2f(uv.s[2*i+0]) + bf2f(gu.s[2*i+0]) + relY*r0[2*i+0] + relX*r1[2*i+0];
        float h1 = bf2f(uv.s[2*i+1]) + bf2f(gu.s[2*i+1]) + relY*r0[2*i+1] + relX*r1[2*i+1];
        ov[i] = cvt_pk_bf16(fmaxf(h0, 0.0f), fmaxf(h1, 0.0f));
      }
      *(uint4*)&A1[swz256i(m, c)] = make_uint4(ov[0],ov[1],ov[2],ov[3]);
    }
  }
  __syncthreads();                                   // sync3

  // ---- phase 3: layer 2 [64x256]@[256x128]; wave: mt=w>>1, n-half=w&1 ----
  const int mt = w >> 1, nh = w & 1;
  f32x4 acc2[4];
  #pragma unroll
  for (int nt=0; nt<4; nt++) acc2[nt] = f32x4{0.f,0.f,0.f,0.f};
  #pragma unroll
  for (int kt=0; kt<8; kt++){
    bf16x8 a = ld8(&A1[swz256i(mt*16 + l15, kt*32 + quad*8)]);
    #pragma unroll
    for (int nt=0; nt<4; nt++){
      bf16x8 b = ld8(&W2t[(size_t)(nh*64 + nt*16 + l15)*256 + kt*32 + quad*8]);
      acc2[nt] = __builtin_amdgcn_mfma_f32_16x16x32_bf16(a, b, acc2[nt], 0,0,0);
    }
  }
  __syncthreads();                                   // sync4 (A1 reads done)

  // ---- phase 4: W3 preload, h2 -> A2 (aliases A1, swizzled stride 128) ----
  bf16x8 b3f[4];
  #pragma unroll
  for (int kt=0; kt<4; kt++)
    b3f[kt] = ld8(&W3t[(size_t)(nh*16 + l15)*128 + kt*32 + quad*8]);
  {
    #pragma unroll
    for (int nt=0; nt<4; nt++){
      int n = nh*64 + nt*16 + l15;
      float bv = b2v[n];
      #pragma unroll
      for (int r=0; r<4; r++)
        A1[swz128i(mt*16 + quad*4 + r, n)] = f2bf(fmaxf(acc2[nt][r] + bv, 0.0f));
    }
  }
  __syncthreads();                                   // sync5

  // ---- phase 5: layer 3 [64x128]@[128x32] + weighted combine ----
  {
    f32x4 acc3 = f32x4{0.f,0.f,0.f,0.f};
    #pragma unroll
    for (int kt=0; kt<4; kt++){
      bf16x8 a = ld8(&A1[swz128i(mt*16 + l15, kt*32 + quad*8)]);
      acc3 = __builtin_amdgcn_mfma_f32_16x16x32_bf16(a, b3f[kt], acc3, 0,0,0);
    }
    // row = mt*16+quad*4+r -> pixel lp=mt*4+quad, branch r; col n = nh*16+l15
    int lp = mt*4 + quad;
    int n  = nh*16 + l15;
    float bb = b3v[n];
    float v = wgt[lp*4+0]*(acc3[0]+bb) + wgt[lp*4+1]*(acc3[1]+bb)
            + wgt[lp*4+2]*(acc3[2]+bb) + wgt[lp*4+3]*(acc3[3]+bb);
    outp[(size_t)n*65536 + (size_t)Y*256 + X0 + lp] = v;
  }
}

extern "C" void kernel_launch(void* const* d_in, const int* in_sizes, int n_in,
                              void* d_out, int out_size, void* d_ws, size_t ws_size,
                              hipStream_t stream)
{
  const float* feat     = (const float*)d_in[0];
  const float* lr_guide = (const float*)d_in[1];
  const float* hr_guide = (const float*)d_in[2];
  const float* W1       = (const float*)d_in[3];
  const float* b1       = (const float*)d_in[4];
  const float* W2       = (const float*)d_in[5];
  const float* b2       = (const float*)d_in[6];
  const float* W3       = (const float*)d_in[7];
  const float* b3       = (const float*)d_in[8];
  float* outp = (float*)d_out;

  char* ws = (char*)d_ws;
  ushort* W1t = (ushort*)(ws);                          // 196608 B
  ushort* W2t = (ushort*)(ws + 196608);                 //  65536 B
  ushort* W3t = (ushort*)(ws + 262144);                 //   8192 B
  ushort* Ft  = (ushort*)(ws + 270336);                 // 16384*256*2 = 8388608 B
  ushort* Ub  = (ushort*)(ws + 270336 + 8388608);       // 16384*256*2 = 8388608 B

  prep<<<896, 256, 0, stream>>>(W1, W2, W3, lr_guide, feat, W1t, W2t, W3t, Ft);
  u_gemm<<<1024, 256, 0, stream>>>(Ft, W1t, Ub);
  main_fused<<<4096, 512, 0, stream>>>(feat, hr_guide, W1, b1, b2, b3,
                                       Ub, W1t, W2t, W3t, outp);
}

// Round 2
// 223.682 us; speedup vs baseline: 1.2776x; 1.2776x over previous
//
#include <hip/hip_runtime.h>
#include <hip/hip_bf16.h>

// ---------------------------------------------------------------------------
// BF_NIR_conv, round 4:
//   k0 prep    : convert W1/W2/W3 -> bf16 N-major + transpose featc -> Ft
//   k1 u_gemm  : U[pos][256] = Ft @ W1[0:256]  (A-frags hoisted, then MFMA)
//   k2 main    : 256-thread / 4-wave tile (known-good r2 skeleton) with:
//                - XOR chunk-swizzle perm(row)=(2r+(r>>2))&7  (all <=2-way)
//                - hr_guide loaded straight into MFMA A-fragments (no staging)
//                - Gt aliased into A1 rows 32..47 -> 34.5 KB LDS, 4 blocks/CU
//                - batch fragment preloads (never inline in MFMA loops)
// ---------------------------------------------------------------------------

using bf16x8 = __attribute__((ext_vector_type(8))) __bf16;
using f32x4  = __attribute__((ext_vector_type(4))) float;

__device__ __forceinline__ float bf2f(unsigned short u){
  unsigned int x = ((unsigned int)u) << 16;
  return __builtin_bit_cast(float, x);
}
__device__ __forceinline__ unsigned short f2bf(float f){
  unsigned int x = __builtin_bit_cast(unsigned int, f);
  unsigned int r = x + 0x7fffu + ((x >> 16) & 1u);
  return (unsigned short)(r >> 16);
}
__device__ __forceinline__ unsigned int cvt_pk_bf16(float lo, float hi){
  unsigned int r;
  asm("v_cvt_pk_bf16_f32 %0, %1, %2" : "=v"(r) : "v"(lo), "v"(hi));
  return r;
}
__device__ __forceinline__ bf16x8 ld8(const ushort* p){
  uint4 r = *(const uint4*)p;
  return __builtin_bit_cast(bf16x8, r);
}

// XOR swizzle at 16B-chunk granularity.  perm(row) = (2*row + (row>>2)) & 7:
//  - C/D scatter rows {quad*4+r}: perm = (quad + 2r)&7 -> 4 distinct  (writes <=2-way)
//  - consecutive rows (reads):    perm = (C + 2i)&7    -> 4 distinct  (reads 8/group)
__device__ __forceinline__ int swzA(int row, int col){   // stride 256
  int p = ((row << 1) + (row >> 2)) & 7;
  return row*256 + (col ^ (p << 3));
}
__device__ __forceinline__ int swzB(int row, int col){   // stride 128
  int p = ((row << 1) + (row >> 2)) & 7;
  return row*128 + (col ^ (p << 3));
}
__device__ __forceinline__ int swzT(int row, int c){     // prep transpose tile
  return row*256 + ((c & ~0x38) | ((((c>>3) + (c>>6) + row) & 7) << 3));
}

struct RowMeta { int spos; float relY, relX; };
__device__ __forceinline__ RowMeta row_meta(int Y, int X, int br){
  int ivx = br >> 1, ivy = br & 1;   // branch order: (vx,vy)=(-,-),(-,+),(+,-),(+,+)
  int validY, iy; float relY;
  if (ivx == 0){ validY = (Y >= 1);   iy = (Y-1) >> 1; relY = (Y & 1) ?  0.5f :  1.5f; }
  else         { validY = (Y <= 254); iy = (Y+1) >> 1; relY = (Y & 1) ? -1.5f : -0.5f; }
  int validX, ix; float relX;
  if (ivy == 0){ validX = (X >= 1);   ix = (X-1) >> 1; relX = (X & 1) ?  0.5f :  1.5f; }
  else         { validX = (X <= 254); ix = (X+1) >> 1; relX = (X & 1) ? -1.5f : -0.5f; }
  RowMeta r;
  if (validY && validX){ r.spos = iy*128 + ix; r.relY = relY; r.relX = relX; }
  else { r.spos = -1; r.relY = (float)Y + 0.5f - 128.0f; r.relX = (float)X + 0.5f - 128.0f; }
  return r;
}

// --- k0: weight convert + featc transpose ----------------------------------
__global__ __launch_bounds__(256) void prep(
    const float* __restrict__ W1, const float* __restrict__ W2,
    const float* __restrict__ W3,
    const float* __restrict__ lr_guide, const float* __restrict__ feat,
    ushort* __restrict__ W1t,   // [256][384]
    ushort* __restrict__ W2t,   // [128][256]
    ushort* __restrict__ W3t,   // [32][128]
    ushort* __restrict__ Ft)    // [16384][256]
{
  __shared__ ushort T[32*256];
  const int b = blockIdx.x, t = threadIdx.x;
  if (b < 512){
    const int pos0 = b*32;
    #pragma unroll
    for (int i=0;i<32;i++){
      int k = i*8 + (t>>5), pos = t & 31;
      const float* src = (k < 128) ? lr_guide : feat;
      T[swzT(pos, k)] = f2bf(src[(size_t)(k & 127)*16384 + pos0 + pos]);
    }
    __syncthreads();
    const int pos = t>>3, ul = t&7;
    #pragma unroll
    for (int jj=0;jj<4;jj++){
      int c = ul*32 + jj*8;
      union { uint4 v; ushort s[8]; } x;
      x.v = *(const uint4*)&T[swzT(pos, c)];
      *(uint4*)&Ft[(size_t)(pos0+pos)*256 + c] = x.v;
    }
  } else {
    int i = (b-512)*256 + t;                       // 384 blocks -> i < 98304
    { int k = i >> 8, n = i & 255; W1t[n*384 + k] = f2bf(W1[i]); }
    if (i < 32768){ int k = i >> 7, n = i & 127; W2t[n*256 + k] = f2bf(W2[i]); }
    if (i < 4096) { int k = i >> 5, n = i & 31;  W3t[n*128 + k] = f2bf(W3[i]); }
  }
}

// --- k1: U GEMM: A-frags hoisted upfront, B (L2-hot) batched per kt ---------
__global__ __launch_bounds__(256) void u_gemm(
    const ushort* __restrict__ Ft, const ushort* __restrict__ W1t,
    ushort* __restrict__ U)                        // [16384][256]
{
  const int t = threadIdx.x;
  const int w = t >> 6, lane = t & 63, quad = lane >> 4, l15 = lane & 15;
  const int pos0 = (blockIdx.x >> 1) * 32;
  const int nh   = blockIdx.x & 1;

  bf16x8 af0[8], af1[8];
  #pragma unroll
  for (int kt=0; kt<8; kt++){
    const int ko = kt*32 + quad*8;
    af0[kt] = ld8(&Ft[(size_t)(pos0 +      l15)*256 + ko]);
    af1[kt] = ld8(&Ft[(size_t)(pos0 + 16 + l15)*256 + ko]);
  }
  f32x4 acc[2][2];
  #pragma unroll
  for (int a=0;a<2;a++){ acc[a][0] = f32x4{0.f,0.f,0.f,0.f}; acc[a][1] = f32x4{0.f,0.f,0.f,0.f}; }

  #pragma unroll
  for (int kt=0; kt<8; kt++){
    const int ko = kt*32 + quad*8;
    bf16x8 b0 = ld8(&W1t[(size_t)(nh*128 + w*32 +      l15)*384 + ko]);
    bf16x8 b1 = ld8(&W1t[(size_t)(nh*128 + w*32 + 16 + l15)*384 + ko]);
    acc[0][0] = __builtin_amdgcn_mfma_f32_16x16x32_bf16(af0[kt], b0, acc[0][0], 0,0,0);
    acc[0][1] = __builtin_amdgcn_mfma_f32_16x16x32_bf16(af0[kt], b1, acc[0][1], 0,0,0);
    acc[1][0] = __builtin_amdgcn_mfma_f32_16x16x32_bf16(af1[kt], b0, acc[1][0], 0,0,0);
    acc[1][1] = __builtin_amdgcn_mfma_f32_16x16x32_bf16(af1[kt], b1, acc[1][1], 0,0,0);
  }
  #pragma unroll
  for (int mt=0; mt<2; mt++)
    #pragma unroll
    for (int nt=0; nt<2; nt++){
      int n = nh*128 + w*32 + nt*16 + l15;
      #pragma unroll
      for (int r=0; r<4; r++)
        U[(size_t)(pos0 + mt*16 + quad*4 + r)*256 + n] = f2bf(acc[mt][nt][r]);
    }
}

// --- k2: fused main. 256 threads, 16 pixels x 4 branches = 64 rows ----------
__global__ __launch_bounds__(256, 4) void main_fused(
    const float* __restrict__ feat,      // [128][16384]
    const float* __restrict__ hr_guide,  // [128][65536]
    const float* __restrict__ W1,        // [386][256] fp32 (rel rows 384/385)
    const float* __restrict__ b1v,
    const float* __restrict__ b2v,
    const float* __restrict__ b3v,
    const ushort* __restrict__ U,        // [16384][256] bf16
    const ushort* __restrict__ W1t,      // [256][384] bf16 (N-major)
    const ushort* __restrict__ W2t,      // [128][256] bf16 (N-major)
    const ushort* __restrict__ W3t,      // [32][128]  bf16 (N-major)
    float* __restrict__ outp)            // [32][65536]
{
  // LDS: A1 32 KB (h1; Gt aliased rows 32..47 in phase 0/2a; h2 aliased
  // swzB after sync4) + w1r 2 KB + gcs/wgt 0.5 KB = 34.8 KB -> 4 blocks/CU.
  __shared__ __align__(16) ushort A1[64*256];
  __shared__ __align__(16) float  w1r[2][256];
  __shared__ float gcs[64];
  __shared__ float wgt[64];

  const int t = threadIdx.x;
  const int w = t >> 6, lane = t & 63, quad = lane >> 4, l15 = lane & 15;
  const int Y  = blockIdx.x >> 4;
  const int X0 = (blockIdx.x & 15) << 4;

  const int m   = t >> 2;            // h1 row owned by this thread
  const int cg  = t & 3;             // column group: cols cg*8 + jj*32
  const int pix = m >> 2, br = m & 3;
  RowMeta rm = row_meta(Y, X0 + pix, br);

  // ---- phase 0: U preload, w1r, gc, G-MFMA (A from hr_guide regs) ----
  uint4 uu[8];
  if (rm.spos >= 0){
    const ushort* Up = U + (size_t)rm.spos*256 + cg*8;
    #pragma unroll
    for (int jj=0; jj<8; jj++) uu[jj] = *(const uint4*)(Up + jj*32);
  } else {
    #pragma unroll
    for (int jj=0; jj<8; jj++) uu[jj] = make_uint4(0u,0u,0u,0u);
  }

  w1r[0][t] = W1[384*256 + t];
  w1r[1][t] = W1[385*256 + t];

  if (t < 64){
    RowMeta g = row_meta(Y, X0 + (t>>2), t & 3);
    float gc = 0.0f;
    if (g.spos >= 0){
      int bpos = (Y>>1)*128 + ((X0 + (t>>2)) >> 1);
      #pragma unroll
      for (int cc=0; cc<3; cc++)
        gc += feat[(size_t)(124+cc)*16384 + bpos] * feat[(size_t)(124+cc)*16384 + g.spos];
    }
    gcs[t] = gc;
  }

  {
    // A-fragment straight from global: lane(l15,quad) = pixel l15, ch-slice
    const float* hg = hr_guide + (size_t)Y*256 + X0 + l15;
    bf16x8 ha[4];
    #pragma unroll
    for (int kt=0; kt<4; kt++){
      float v[8];
      #pragma unroll
      for (int j=0; j<8; j++) v[j] = hg[(size_t)(kt*32 + quad*8 + j)*65536];
      uint4 pk;
      pk.x = cvt_pk_bf16(v[0],v[1]); pk.y = cvt_pk_bf16(v[2],v[3]);
      pk.z = cvt_pk_bf16(v[4],v[5]); pk.w = cvt_pk_bf16(v[6],v[7]);
      ha[kt] = __builtin_bit_cast(bf16x8, pk);
    }
    f32x4 accg[4];
    #pragma unroll
    for (int nt=0; nt<4; nt++) accg[nt] = f32x4{0.f,0.f,0.f,0.f};
    #pragma unroll
    for (int kt=0; kt<4; kt++)
      #pragma unroll
      for (int nt=0; nt<4; nt++){
        bf16x8 b = ld8(&W1t[(size_t)(w*64 + nt*16 + l15)*384 + 256 + kt*32 + quad*8]);
        accg[nt] = __builtin_amdgcn_mfma_f32_16x16x32_bf16(ha[kt], b, accg[nt], 0,0,0);
      }
    // Gt aliased at A1 rows 32..47: row = 32 + pixel (C/D row = quad*4+r)
    #pragma unroll
    for (int nt=0; nt<4; nt++){
      int n = w*64 + nt*16 + l15;
      float bv = b1v[n];
      #pragma unroll
      for (int r=0; r<4; r++)
        A1[swzA(32 + quad*4 + r, n)] = f2bf(accg[nt][r] + bv);
    }
  }
  __syncthreads();                                   // sync1: Gt/gcs/w1r ready

  // ---- phase 2a: Gt -> regs (must precede h1 writes that overwrite alias) ----
  uint4 gt[8];
  #pragma unroll
  for (int jj=0; jj<8; jj++)
    gt[jj] = *(const uint4*)&A1[swzA(32 + pix, cg*8 + jj*32)];
  if (t < 16){
    float g0 = gcs[t*4+0], g1 = gcs[t*4+1], g2 = gcs[t*4+2], g3 = gcs[t*4+3];
    float mx = fmaxf(fmaxf(g0,g1), fmaxf(g2,g3));
    float e0 = __expf(g0-mx), e1 = __expf(g1-mx), e2 = __expf(g2-mx), e3 = __expf(g3-mx);
    float inv = 1.0f/(e0+e1+e2+e3);
    wgt[t*4+0]=e0*inv; wgt[t*4+1]=e1*inv; wgt[t*4+2]=e2*inv; wgt[t*4+3]=e3*inv;
  }
  __syncthreads();                                   // sync2: Gt reads done

  // ---- phase 2b: h1 assembly into A1 ----
  {
    const float relY = rm.relY, relX = rm.relX;
    #pragma unroll
    for (int jj=0; jj<8; jj++){
      const int c = cg*8 + jj*32;
      union { uint4 v; ushort s[8]; } gu, uv;
      gu.v = gt[jj];
      uv.v = uu[jj];
      float r0[8], r1[8];
      *(float4*)&r0[0] = *(const float4*)&w1r[0][c];
      *(float4*)&r0[4] = *(const float4*)&w1r[0][c+4];
      *(float4*)&r1[0] = *(const float4*)&w1r[1][c];
      *(float4*)&r1[4] = *(const float4*)&w1r[1][c+4];
      unsigned int ov[4];
      #pragma unroll
      for (int i=0; i<4; i++){
        float h0 = bf2f(uv.s[2*i+0]) + bf2f(gu.s[2*i+0]) + relY*r0[2*i+0] + relX*r1[2*i+0];
        float h1 = bf2f(uv.s[2*i+1]) + bf2f(gu.s[2*i+1]) + relY*r0[2*i+1] + relX*r1[2*i+1];
        ov[i] = cvt_pk_bf16(fmaxf(h0, 0.0f), fmaxf(h1, 0.0f));
      }
      *(uint4*)&A1[swzA(m, c)] = make_uint4(ov[0],ov[1],ov[2],ov[3]);
    }
  }
  __syncthreads();                                   // sync3: h1 ready

  // ---- phase 3: layer 2 [64x256]@[256x128]; wave owns 32 N-cols ----
  // Batch-load all B fragments FIRST (L2-hot), then pure LDS+MFMA loop.
  bf16x8 b2f[8][2];
  #pragma unroll
  for (int kt=0; kt<8; kt++)
    #pragma unroll
    for (int nt=0; nt<2; nt++)
      b2f[kt][nt] = ld8(&W2t[(size_t)(w*32 + nt*16 + l15)*256 + kt*32 + quad*8]);

  f32x4 acc2[4][2];
  #pragma unroll
  for (int mt=0; mt<4; mt++)
    #pragma unroll
    for (int nt=0; nt<2; nt++) acc2[mt][nt] = f32x4{0.f,0.f,0.f,0.f};

  __builtin_amdgcn_s_setprio(1);
  #pragma unroll
  for (int mt=0; mt<4; mt++)
    #pragma unroll
    for (int kt=0; kt<8; kt++){
      bf16x8 a = ld8(&A1[swzA(mt*16 + l15, kt*32 + quad*8)]);
      #pragma unroll
      for (int nt=0; nt<2; nt++)
        acc2[mt][nt] = __builtin_amdgcn_mfma_f32_16x16x32_bf16(a, b2f[kt][nt], acc2[mt][nt], 0,0,0);
    }
  __builtin_amdgcn_s_setprio(0);
  __syncthreads();                                   // sync4: A1 reads done

  // ---- phase 4: W3 preload, h2 -> A1 alias (swzB, stride 128) ----
  bf16x8 b3f[4][2];
  #pragma unroll
  for (int kt=0; kt<4; kt++)
    #pragma unroll
    for (int nt=0; nt<2; nt++)
      b3f[kt][nt] = ld8(&W3t[(size_t)(nt*16 + l15)*128 + kt*32 + quad*8]);
  {
    float bias0 = b2v[w*32 + l15], bias1 = b2v[w*32 + 16 + l15];
    #pragma unroll
    for (int mt=0; mt<4; mt++)
      #pragma unroll
      for (int nt=0; nt<2; nt++){
        int n = w*32 + nt*16 + l15;
        float bv = nt ? bias1 : bias0;
        #pragma unroll
        for (int r=0; r<4; r++)
          A1[swzB(mt*16 + quad*4 + r, n)] = f2bf(fmaxf(acc2[mt][nt][r] + bv, 0.0f));
      }
  }
  __syncthreads();                                   // sync5: h2 ready

  // ---- phase 5: layer 3 [64x128]@[128x32] + weighted combine ----
  {
    f32x4 acc3[2] = { f32x4{0.f,0.f,0.f,0.f}, f32x4{0.f,0.f,0.f,0.f} };
    #pragma unroll
    for (int kt=0; kt<4; kt++){
      bf16x8 a = ld8(&A1[swzB(w*16 + l15, kt*32 + quad*8)]);
      #pragma unroll
      for (int nt=0; nt<2; nt++)
        acc3[nt] = __builtin_amdgcn_mfma_f32_16x16x32_bf16(a, b3f[kt][nt], acc3[nt], 0,0,0);
    }
    // row = w*16+quad*4+r -> pixel lp=w*4+quad, branch r
    int lp = w*4 + quad;
    int X = X0 + lp;
    float w0 = wgt[lp*4+0], w1 = wgt[lp*4+1], w2 = wgt[lp*4+2], w3 = wgt[lp*4+3];
    #pragma unroll
    for (int nt=0; nt<2; nt++){
      int n = nt*16 + l15;
      float bb = b3v[n];
      float v = w0*(acc3[nt][0]+bb) + w1*(acc3[nt][1]+bb)
              + w2*(acc3[nt][2]+bb) + w3*(acc3[nt][3]+bb);
      outp[(size_t)n*65536 + (size_t)Y*256 + X] = v;
    }
  }
}

extern "C" void kernel_launch(void* const* d_in, const int* in_sizes, int n_in,
                              void* d_out, int out_size, void* d_ws, size_t ws_size,
                              hipStream_t stream)
{
  const float* feat     = (const float*)d_in[0];
  const float* lr_guide = (const float*)d_in[1];
  const float* hr_guide = (const float*)d_in[2];
  const float* W1       = (const float*)d_in[3];
  const float* b1       = (const float*)d_in[4];
  const float* W2       = (const float*)d_in[5];
  const float* b2       = (const float*)d_in[6];
  const float* W3       = (const float*)d_in[7];
  const float* b3       = (const float*)d_in[8];
  float* outp = (float*)d_out;

  char* ws = (char*)d_ws;
  ushort* W1t = (ushort*)(ws);                          // 196608 B
  ushort* W2t = (ushort*)(ws + 196608);                 //  65536 B
  ushort* W3t = (ushort*)(ws + 262144);                 //   8192 B
  ushort* Ft  = (ushort*)(ws + 270336);                 // 8388608 B
  ushort* Ub  = (ushort*)(ws + 270336 + 8388608);       // 8388608 B

  prep<<<896, 256, 0, stream>>>(W1, W2, W3, lr_guide, feat, W1t, W2t, W3t, Ft);
  u_gemm<<<1024, 256, 0, stream>>>(Ft, W1t, Ub);
  main_fused<<<4096, 256, 0, stream>>>(feat, hr_guide, W1, b1, b2, b3,
                                       Ub, W1t, W2t, W3t, outp);
}

// Round 3
// 188.874 us; speedup vs baseline: 1.5130x; 1.1843x over previous
//
#include <hip/hip_runtime.h>
#include <hip/hip_bf16.h>

// ---------------------------------------------------------------------------
// BF_NIR_conv, round 5: round-0 skeleton + verified fixes only.
//   k0 convert : W1/W2/W3 -> bf16 N-major (r0 verbatim)
//   k1 u_gemm  : U[pos][256] = featc[pos] @ W1[0:256]; self-staged fp32->LDS,
//                512 blocks (32-pos tiles), B-frags batch-hoisted
//   k2 main    : r0 structure (hr staged via float4->LDS, separate Gt,
//                batch-hoisted fragments) + chunk-XOR swizzle (all patterns
//                hand-verified <=2-way) + cvt_pk pack + XCD block swizzle
// ---------------------------------------------------------------------------

using bf16x8 = __attribute__((ext_vector_type(8))) __bf16;
using f32x4  = __attribute__((ext_vector_type(4))) float;

__device__ __forceinline__ float bf2f(unsigned short u){
  unsigned int x = ((unsigned int)u) << 16;
  return __builtin_bit_cast(float, x);
}
__device__ __forceinline__ unsigned short f2bf(float f){
  unsigned int x = __builtin_bit_cast(unsigned int, f);
  unsigned int r = x + 0x7fffu + ((x >> 16) & 1u);
  return (unsigned short)(r >> 16);
}
__device__ __forceinline__ unsigned int cvt_pk_bf16(float lo, float hi){
  unsigned int r;
  asm("v_cvt_pk_bf16_f32 %0, %1, %2" : "=v"(r) : "v"(lo), "v"(hi));
  return r;
}
__device__ __forceinline__ bf16x8 ld8(const ushort* p){
  uint4 r = *(const uint4*)p;
  return __builtin_bit_cast(bf16x8, r);
}

// 16B-chunk XOR swizzle, perm(row) = (2*row + (row>>2)) & 7.
// Verified balanced (<=2-way) for: h1 writes/reads (interleaved cols
// cg*8+jj*32), C/D scatter writes (rows quad*4+r), Gt broadcast reads,
// G A-frag reads, phase3/5 reads.  Keeps 16B alignment, zero padding.
__device__ __forceinline__ int swzA(int row, int col){   // stride 256 ushort
  int p = ((row << 1) + (row >> 2)) & 7;
  return row*256 + (col ^ (p << 3));
}
__device__ __forceinline__ int swzB(int row, int col){   // stride 128 ushort
  int p = ((row << 1) + (row >> 2)) & 7;
  return row*128 + (col ^ (p << 3));
}

struct RowMeta { int spos; float relY, relX; };
__device__ __forceinline__ RowMeta row_meta(int Y, int X, int br){
  int ivx = br >> 1, ivy = br & 1;   // branch order: (vx,vy)=(-,-),(-,+),(+,-),(+,+)
  int validY, iy; float relY;
  if (ivx == 0){ validY = (Y >= 1);   iy = (Y-1) >> 1; relY = (Y & 1) ?  0.5f :  1.5f; }
  else         { validY = (Y <= 254); iy = (Y+1) >> 1; relY = (Y & 1) ? -1.5f : -0.5f; }
  int validX, ix; float relX;
  if (ivy == 0){ validX = (X >= 1);   ix = (X-1) >> 1; relX = (X & 1) ?  0.5f :  1.5f; }
  else         { validX = (X <= 254); ix = (X+1) >> 1; relX = (X & 1) ? -1.5f : -0.5f; }
  RowMeta r;
  if (validY && validX){ r.spos = iy*128 + ix; r.relY = relY; r.relX = relX; }
  else { r.spos = -1; r.relY = (float)Y + 0.5f - 128.0f; r.relX = (float)X + 0.5f - 128.0f; }
  return r;
}

// --- k0: convert weights to bf16, transposed to [N][K] ----------------------
__global__ __launch_bounds__(256) void convert_weights(
    const float* __restrict__ W1, const float* __restrict__ W2,
    const float* __restrict__ W3,
    ushort* __restrict__ W1t,   // [256][384]
    ushort* __restrict__ W2t,   // [128][256]
    ushort* __restrict__ W3t)   // [32][128]
{
  int i = blockIdx.x*256 + threadIdx.x;           // grid = 384 blocks -> i < 98304
  { int k = i >> 8, n = i & 255; W1t[n*384 + k] = f2bf(W1[i]); }
  if (i < 32768){ int k = i >> 7, n = i & 127; W2t[n*256 + k] = f2bf(W2[i]); }
  if (i < 4096) { int k = i >> 5, n = i & 31;  W3t[n*128 + k] = f2bf(W3[i]); }
}

// --- k1: U GEMM, 512 blocks x 32-pos tiles, full-K LDS stage ----------------
__global__ __launch_bounds__(256) void u_gemm(
    const float* __restrict__ lr_guide, const float* __restrict__ feat,
    const ushort* __restrict__ W1t,
    ushort* __restrict__ U)                        // [16384][256]
{
  __shared__ ushort T[32*256];                     // [pos][k], swzA
  const int t = threadIdx.x;
  const int w = t >> 6, lane = t & 63, quad = lane >> 4, l15 = lane & 15;
  const int pos0 = blockIdx.x * 32;

  #pragma unroll
  for (int i=0; i<32; i++){                        // k = i*8 + t>>5, p = t&31
    int k = i*8 + (t>>5), p = t & 31;
    const float* src = (k < 128) ? lr_guide : feat;
    T[swzA(p, k)] = f2bf(src[(size_t)(k & 127)*16384 + pos0 + p]);
  }
  __syncthreads();

  f32x4 acc[2][4];
  #pragma unroll
  for (int mt=0; mt<2; mt++)
    #pragma unroll
    for (int nt=0; nt<4; nt++) acc[mt][nt] = f32x4{0.f,0.f,0.f,0.f};

  #pragma unroll
  for (int kt=0; kt<8; kt++){
    const int ko = kt*32 + quad*8;
    bf16x8 bt[4];
    #pragma unroll
    for (int nt=0; nt<4; nt++)
      bt[nt] = ld8(&W1t[(size_t)(w*64 + nt*16 + l15)*384 + ko]);
    bf16x8 a0 = ld8(&T[swzA(l15,      ko)]);
    bf16x8 a1 = ld8(&T[swzA(16 + l15, ko)]);
    #pragma unroll
    for (int nt=0; nt<4; nt++){
      acc[0][nt] = __builtin_amdgcn_mfma_f32_16x16x32_bf16(a0, bt[nt], acc[0][nt], 0,0,0);
      acc[1][nt] = __builtin_amdgcn_mfma_f32_16x16x32_bf16(a1, bt[nt], acc[1][nt], 0,0,0);
    }
  }
  #pragma unroll
  for (int mt=0; mt<2; mt++)
    #pragma unroll
    for (int nt=0; nt<4; nt++){
      int n = w*64 + nt*16 + l15;
      #pragma unroll
      for (int r=0; r<4; r++)
        U[(size_t)(pos0 + mt*16 + quad*4 + r)*256 + n] = f2bf(acc[mt][nt][r]);
    }
}

// --- k2: fused main. 256 threads, 16 pixels x 4 branches = 64 rows ----------
__global__ __launch_bounds__(256, 3) void main_fused(
    const float* __restrict__ feat,      // [128][16384]
    const float* __restrict__ hr_guide,  // [128][65536]
    const float* __restrict__ W1,        // [386][256] fp32 (rel rows 384/385)
    const float* __restrict__ b1v,
    const float* __restrict__ b2v,
    const float* __restrict__ b3v,
    const ushort* __restrict__ U,        // [16384][256] bf16
    const ushort* __restrict__ W1t,      // [256][384] bf16 (N-major)
    const ushort* __restrict__ W2t,      // [128][256] bf16 (N-major)
    const ushort* __restrict__ W3t,      // [32][128]  bf16 (N-major)
    float* __restrict__ outp)            // [32][65536]
{
  // LDS: A1 32 KB (hr-stage [16][128] swzB aliased at base; h2 [64][128]
  // swzB aliased after sync4) + Gt 8 KB + w1r 2 KB + gcs/wgt 0.5 KB
  // = 42.5 KB -> 3 blocks/CU (r0 occupancy, r0-known-good structure).
  __shared__ __align__(16) ushort A1[64*256];
  __shared__ __align__(16) ushort Gt[16*256];
  __shared__ __align__(16) float  w1r[2][256];
  __shared__ float gcs[64];
  __shared__ float wgt[64];

  const int t = threadIdx.x;
  const int w = t >> 6, lane = t & 63, quad = lane >> 4, l15 = lane & 15;
  // XCD-bijective swizzle: 4096 blocks = 8 XCDs x 512 contiguous
  const int wg = (blockIdx.x & 7) * 512 + (blockIdx.x >> 3);
  const int Y  = wg >> 4;
  const int X0 = (wg & 15) << 4;

  const int m   = t >> 2;            // h1 row owned by this thread
  const int cg  = t & 3;             // interleaved cols: c = cg*8 + jj*32
  const int pix = m >> 2, br = m & 3;
  RowMeta rm = row_meta(Y, X0 + pix, br);

  // ---- phase 0: U preload, G B-frags (global, overlap staging), hr->LDS ----
  uint4 uu[8];
  if (rm.spos >= 0){
    const ushort* Up = U + (size_t)rm.spos*256 + cg*8;
    #pragma unroll
    for (int jj=0; jj<8; jj++) uu[jj] = *(const uint4*)(Up + jj*32);
  } else {
    #pragma unroll
    for (int jj=0; jj<8; jj++) uu[jj] = make_uint4(0u,0u,0u,0u);
  }

  bf16x8 gb[4][4];                   // G B-fragments, hoisted (pure global)
  #pragma unroll
  for (int kt=0; kt<4; kt++)
    #pragma unroll
    for (int nt=0; nt<4; nt++)
      gb[kt][nt] = ld8(&W1t[(size_t)(w*64 + nt*16 + l15)*384 + 256 + kt*32 + quad*8]);

  {                                  // hr staging: [pix][ch] swzB at A1 base
    #pragma unroll
    for (int i=0; i<2; i++){
      int id = i*256 + t;            // 0..511
      int ch = id >> 2, xq = id & 3;
      float4 v = *(const float4*)(hr_guide + (size_t)ch*65536 + Y*256 + X0 + xq*4);
      A1[swzB(xq*4+0, ch)] = f2bf(v.x);
      A1[swzB(xq*4+1, ch)] = f2bf(v.y);
      A1[swzB(xq*4+2, ch)] = f2bf(v.z);
      A1[swzB(xq*4+3, ch)] = f2bf(v.w);
    }
  }
  w1r[0][t] = W1[384*256 + t];
  w1r[1][t] = W1[385*256 + t];

  if (t < 64){
    RowMeta g = row_meta(Y, X0 + (t>>2), t & 3);
    float gc = 0.0f;
    if (g.spos >= 0){
      int bpos = (Y>>1)*128 + ((X0 + (t>>2)) >> 1);
      #pragma unroll
      for (int cc=0; cc<3; cc++)
        gc += feat[(size_t)(124+cc)*16384 + bpos] * feat[(size_t)(124+cc)*16384 + g.spos];
    }
    gcs[t] = gc;
  }
  __syncthreads();                                   // sync1

  // ---- phase 1: softmax weights + G MFMA (M=16 pix, N=256, K=128) ----
  if (t < 16){
    float g0 = gcs[t*4+0], g1 = gcs[t*4+1], g2 = gcs[t*4+2], g3 = gcs[t*4+3];
    float mx = fmaxf(fmaxf(g0,g1), fmaxf(g2,g3));
    float e0 = __expf(g0-mx), e1 = __expf(g1-mx), e2 = __expf(g2-mx), e3 = __expf(g3-mx);
    float inv = 1.0f/(e0+e1+e2+e3);
    wgt[t*4+0]=e0*inv; wgt[t*4+1]=e1*inv; wgt[t*4+2]=e2*inv; wgt[t*4+3]=e3*inv;
  }
  {
    f32x4 accg[4];
    #pragma unroll
    for (int nt=0; nt<4; nt++) accg[nt] = f32x4{0.f,0.f,0.f,0.f};
    #pragma unroll
    for (int kt=0; kt<4; kt++){
      bf16x8 a = ld8(&A1[swzB(l15, kt*32 + quad*8)]);          // hr-stage
      #pragma unroll
      for (int nt=0; nt<4; nt++)
        accg[nt] = __builtin_amdgcn_mfma_f32_16x16x32_bf16(a, gb[kt][nt], accg[nt], 0,0,0);
    }
    #pragma unroll
    for (int nt=0; nt<4; nt++){
      int n = w*64 + nt*16 + l15;
      float bv = b1v[n];
      #pragma unroll
      for (int r=0; r<4; r++)
        Gt[swzA(quad*4+r, n)] = f2bf(accg[nt][r] + bv);        // C/D row=quad*4+r
    }
  }
  __syncthreads();                                   // sync2

  // ---- phase 2: b2f hoist (global) + h1 assembly into A1 ----
  bf16x8 b2f[8][2];
  #pragma unroll
  for (int kt=0; kt<8; kt++)
    #pragma unroll
    for (int nt=0; nt<2; nt++)
      b2f[kt][nt] = ld8(&W2t[(size_t)(w*32 + nt*16 + l15)*256 + kt*32 + quad*8]);

  {
    const float relY = rm.relY, relX = rm.relX;
    #pragma unroll
    for (int jj=0; jj<8; jj++){
      const int c = cg*8 + jj*32;
      union { uint4 v; ushort s[8]; } gu, uv;
      gu.v = *(const uint4*)&Gt[swzA(pix, c)];
      uv.v = uu[jj];
      float r0[8], r1[8];
      *(float4*)&r0[0] = *(const float4*)&w1r[0][c];
      *(float4*)&r0[4] = *(const float4*)&w1r[0][c+4];
      *(float4*)&r1[0] = *(const float4*)&w1r[1][c];
      *(float4*)&r1[4] = *(const float4*)&w1r[1][c+4];
      unsigned int ov[4];
      #pragma unroll
      for (int i=0; i<4; i++){
        float h0 = bf2f(uv.s[2*i+0]) + bf2f(gu.s[2*i+0]) + relY*r0[2*i+0] + relX*r1[2*i+0];
        float h1 = bf2f(uv.s[2*i+1]) + bf2f(gu.s[2*i+1]) + relY*r0[2*i+1] + relX*r1[2*i+1];
        ov[i] = cvt_pk_bf16(fmaxf(h0, 0.0f), fmaxf(h1, 0.0f));
      }
      *(uint4*)&A1[swzA(m, c)] = make_uint4(ov[0],ov[1],ov[2],ov[3]);
    }
  }
  __syncthreads();                                   // sync3

  // ---- phase 3: layer 2 [64x256]@[256x128]; wave owns 32 N-cols ----
  f32x4 acc2[4][2];
  #pragma unroll
  for (int mt=0; mt<4; mt++)
    #pragma unroll
    for (int nt=0; nt<2; nt++) acc2[mt][nt] = f32x4{0.f,0.f,0.f,0.f};

  __builtin_amdgcn_s_setprio(1);
  #pragma unroll
  for (int mt=0; mt<4; mt++)
    #pragma unroll
    for (int kt=0; kt<8; kt++){
      bf16x8 a = ld8(&A1[swzA(mt*16 + l15, kt*32 + quad*8)]);
      #pragma unroll
      for (int nt=0; nt<2; nt++)
        acc2[mt][nt] = __builtin_amdgcn_mfma_f32_16x16x32_bf16(a, b2f[kt][nt], acc2[mt][nt], 0,0,0);
    }
  __builtin_amdgcn_s_setprio(0);
  __syncthreads();                                   // sync4: A1 reads done

  // ---- phase 4: W3 preload, h2 -> A1 alias (swzB, stride 128) ----
  bf16x8 b3f[4][2];
  #pragma unroll
  for (int kt=0; kt<4; kt++)
    #pragma unroll
    for (int nt=0; nt<2; nt++)
      b3f[kt][nt] = ld8(&W3t[(size_t)(nt*16 + l15)*128 + kt*32 + quad*8]);
  {
    float bias0 = b2v[w*32 + l15], bias1 = b2v[w*32 + 16 + l15];
    #pragma unroll
    for (int mt=0; mt<4; mt++)
      #pragma unroll
      for (int nt=0; nt<2; nt++){
        int n = w*32 + nt*16 + l15;
        float bv = nt ? bias1 : bias0;
        #pragma unroll
        for (int r=0; r<4; r++)
          A1[swzB(mt*16 + quad*4 + r, n)] = f2bf(fmaxf(acc2[mt][nt][r] + bv, 0.0f));
      }
  }
  __syncthreads();                                   // sync5: h2 ready

  // ---- phase 5: layer 3 [64x128]@[128x32] + weighted combine ----
  {
    f32x4 acc3[2] = { f32x4{0.f,0.f,0.f,0.f}, f32x4{0.f,0.f,0.f,0.f} };
    #pragma unroll
    for (int kt=0; kt<4; kt++){
      bf16x8 a = ld8(&A1[swzB(w*16 + l15, kt*32 + quad*8)]);
      #pragma unroll
      for (int nt=0; nt<2; nt++)
        acc3[nt] = __builtin_amdgcn_mfma_f32_16x16x32_bf16(a, b3f[kt][nt], acc3[nt], 0,0,0);
    }
    // row = w*16+quad*4+r -> pixel lp=w*4+quad, branch r
    int lp = w*4 + quad;
    int X = X0 + lp;
    float w0 = wgt[lp*4+0], w1 = wgt[lp*4+1], w2 = wgt[lp*4+2], w3 = wgt[lp*4+3];
    #pragma unroll
    for (int nt=0; nt<2; nt++){
      int n = nt*16 + l15;
      float bb = b3v[n];
      float v = w0*(acc3[nt][0]+bb) + w1*(acc3[nt][1]+bb)
              + w2*(acc3[nt][2]+bb) + w3*(acc3[nt][3]+bb);
      outp[(size_t)n*65536 + (size_t)Y*256 + X] = v;
    }
  }
}

extern "C" void kernel_launch(void* const* d_in, const int* in_sizes, int n_in,
                              void* d_out, int out_size, void* d_ws, size_t ws_size,
                              hipStream_t stream)
{
  const float* feat     = (const float*)d_in[0];
  const float* lr_guide = (const float*)d_in[1];
  const float* hr_guide = (const float*)d_in[2];
  const float* W1       = (const float*)d_in[3];
  const float* b1       = (const float*)d_in[4];
  const float* W2       = (const float*)d_in[5];
  const float* b2       = (const float*)d_in[6];
  const float* W3       = (const float*)d_in[7];
  const float* b3       = (const float*)d_in[8];
  float* outp = (float*)d_out;

  char* ws = (char*)d_ws;
  ushort* W1t = (ushort*)(ws);                          // 196608 B
  ushort* W2t = (ushort*)(ws + 196608);                 //  65536 B
  ushort* W3t = (ushort*)(ws + 262144);                 //   8192 B
  ushort* Ub  = (ushort*)(ws + 270336);                 // 8388608 B

  convert_weights<<<384, 256, 0, stream>>>(W1, W2, W3, W1t, W2t, W3t);
  u_gemm<<<512, 256, 0, stream>>>(lr_guide, feat, W1t, Ub);
  main_fused<<<4096, 256, 0, stream>>>(feat, hr_guide, W1, b1, b2, b3,
                                       Ub, W1t, W2t, W3t, outp);
}